// Round 17
// baseline (161.575 us; speedup 1.0000x reference)
//
#include <hip/hip_runtime.h>
#include <math.h>

// Problem constants (from reference setup_inputs)
#define BB 64
#define MM 50
#define PP 24564
#define NBLK 96                   // ceil(PP/256)
#define THRESH 0.2f
#define P4 (PP / 4)               // 6141 float4s, exact
#define SLACK 64u                 // ulp slack on the bestv filter
#define NCH 24                    // prior chunks in k_bpo3
#define WMARG 0.151f              // max prior half-extent 0.15 + eps
#define RCPM 8u                   // ulp margin for rcp pre-compare
#define SELCH 8                   // confneg chunks in k_selA
#define SCH4 ((P4 + SELCH - 1) / SELCH)   // 768 float4 = 3072 values per block
#define CAP PP                    // full-capacity collection: never overflows

// SSD loc-encoding L1 term (identical formula/bits in k_main and k_selKF)
__device__ __forceinline__ float l1loc(float4 bxm, float4 pc, float4 pl) {
    float cx = (bxm.x + bxm.z) * 0.5f, cy = (bxm.y + bxm.w) * 0.5f;
    float w = bxm.z - bxm.x, h = bxm.w - bxm.y;
    float g0 = (cx - pc.x) / (pc.z * 0.1f);
    float g1 = (cy - pc.y) / (pc.w * 0.1f);
    float g2 = logf(w / pc.z) * 5.0f;
    float g3 = logf(h / pc.w) * 5.0f;
    return fabsf(pl.x - g0) + fabsf(pl.y - g1) + fabsf(pl.z - g2) + fabsf(pl.w - g3);
}

// ---------------- k_init: zero ghist/ghist2/gcur, init Lm ----------------
__global__ void k_init(int* __restrict__ ghist, int* __restrict__ ghist2,
                       int* __restrict__ gcur, unsigned long long* __restrict__ Lm) {
    int i = blockIdx.x * 256 + threadIdx.x;   // 512*256 = 131072 threads
    if (i < BB * 2048) ghist[i] = 0;
    if (i < BB * 1024) ghist2[i] = 0;
    if (i < BB) gcur[i] = 0;
    if (i < BB * MM) Lm[i] = 0x00000000FFFFFFFFull;   // q=+0.0, ~p with p=0
}

// ---------------- k_main: per-prior argmax + mutual row-max + CE/loc/hist ----------------
// R11 structure: boxes+areas staged once in LDS, bm-only tracking (1 cndmask
// set per iter), box refetched from LDS after the loop for l1loc.
__global__ void k_main(const float4* __restrict__ boxes,
                       const float4* __restrict__ pr_cxcy,
                       const float4* __restrict__ plocs,
                       const float2* __restrict__ scores,
                       unsigned long long* __restrict__ Lm,
                       float* __restrict__ bestv,
                       int* __restrict__ bmv,
                       float* __restrict__ confneg,
                       int* __restrict__ ghist,
                       int* __restrict__ npos_part,
                       float* __restrict__ cpos_part,
                       float* __restrict__ loc_part) {
    int b = blockIdx.y;
    int p = blockIdx.x * 256 + threadIdx.x;
    int tid = threadIdx.x;
    __shared__ float4 sbox[MM];
    __shared__ float sarea[MM];
    __shared__ unsigned long long smax[MM];
    __shared__ int shist[2048];
    __shared__ int si[256];
    __shared__ float s1[256], s2[256];
    for (int i = tid; i < 2048; i += 256) shist[i] = 0;
    if (tid < MM) {
        float4 bxt = boxes[b * MM + tid];
        sbox[tid] = bxt;
        sarea[tid] = (bxt.z - bxt.x) * (bxt.w - bxt.y);
        smax[tid] = 0ull;
    }
    __syncthreads();

    int np = 0;
    float cpos = 0.0f, lloc = 0.0f;
    if (p < PP) {
        float4 pc = pr_cxcy[p];
        float px1 = pc.x - pc.z * 0.5f, py1 = pc.y - pc.w * 0.5f;
        float px2 = pc.x + pc.z * 0.5f, py2 = pc.y + pc.w * 0.5f;
        float pa = (px2 - px1) * (py2 - py1);   // reference rounding (area from corners)
        float binter = 0.0f, bdenom = 1.0f;
        int bm = 0;
        for (int m = 0; m < MM; ++m) {
            float4 bxm = sbox[m];
            float lx = fmaxf(bxm.x, px1), ly = fmaxf(bxm.y, py1);
            float rx = fminf(bxm.z, px2), ry = fminf(bxm.w, py2);
            float iw = fmaxf(rx - lx, 0.0f), ih = fmaxf(ry - ly, 0.0f);
            float inter = iw * ih;
            float den = sarea[m] + pa - inter;
            // inter/den > binter/bdenom  <=>  inter*bdenom > binter*den
            float l = inter * bdenom, r = binter * den;
            if (l > r) { binter = inter; bdenom = den; bm = m; }
        }
        float q = binter / bdenom;   // reference's rounded matrix entry
        size_t idx = (size_t)b * PP + p;
        bestv[idx] = q;
        bmv[idx] = bm;
        unsigned long long key =
            ((unsigned long long)__float_as_uint(q) << 32) | (unsigned int)(~p);
        atomicMax(&smax[bm], key);   // mutual init for row-max pruning
        bool pos = (q >= THRESH);
        float2 sc = scores[idx];
        float mx = fmaxf(sc.x, sc.y);
        float lse = mx + logf(expf(sc.x - mx) + expf(sc.y - mx));
        float conf = pos ? (lse - sc.y) : (lse - sc.x);   // -logp[label]
        float ck = pos ? 0.0f : conf;
        confneg[idx] = ck;
        atomicAdd(&shist[__float_as_uint(ck) >> 20], 1);
        if (pos) {
            np = 1;
            cpos = conf;
            lloc = l1loc(sbox[bm], pc, plocs[idx]);
        }
    }
    si[tid] = np; s1[tid] = cpos; s2[tid] = lloc;
    __syncthreads();
    for (int s = 128; s > 0; s >>= 1) {
        if (tid < s) {
            si[tid] += si[tid + s];
            s1[tid] += s1[tid + s];
            s2[tid] += s2[tid + s];
        }
        __syncthreads();
    }
    if (tid == 0) {
        int o = b * NBLK + blockIdx.x;
        npos_part[o] = si[0];
        cpos_part[o] = s1[0];
        loc_part[o] = s2[0];
    }
    if (tid < MM) {
        unsigned long long v = smax[tid];
        if (v) atomicMax(&Lm[b * MM + tid], v);
    }
    for (int i = tid; i < 2048; i += 256) {
        int c = shist[i];
        if (c) atomicAdd(&ghist[b * 2048 + i], c);
    }
}

// ---------------- k_bpo3: pruned completion, thr-sorted + WAVE-coherent break ----------------
__global__ void k_bpo3(const float4* __restrict__ boxes,
                       const float4* __restrict__ pr_cxcy,
                       const float* __restrict__ bestv,
                       unsigned long long* __restrict__ Lm) {
    int b = blockIdx.y, c = blockIdx.x, tid = threadIdx.x;
    __shared__ float4 sbox[MM];
    __shared__ float sarea[MM];
    __shared__ unsigned thr[MM];
    __shared__ unsigned thrs[MM];         // thr sorted ascending
    __shared__ unsigned char order[MM];   // object index at each sorted rank
    __shared__ unsigned long long smax[MM];
    if (tid < MM) {
        float4 bxt = boxes[b * MM + tid];
        sbox[tid] = bxt;
        sarea[tid] = (bxt.z - bxt.x) * (bxt.w - bxt.y);
        unsigned long long L = Lm[b * MM + tid];
        smax[tid] = L;
        unsigned hi = (unsigned)(L >> 32);
        thr[tid] = (hi > SLACK) ? hi - SLACK : 0u;
    }
    __syncthreads();
    if (tid < MM) {   // rank sort (deterministic, ties by index)
        unsigned tj = thr[tid];
        int rank = 0;
        for (int k = 0; k < MM; ++k) {
            unsigned tk = thr[k];
            if (tk < tj || (tk == tj && k < tid)) rank++;
        }
        order[rank] = (unsigned char)tid;
        thrs[rank] = tj;
    }
    __syncthreads();
    unsigned minthr = thrs[0];
    volatile unsigned long long* vsm = smax;
    const float4* bv4 = (const float4*)(bestv + (size_t)b * PP);
    int i = c * 256 + tid;
    // qb per element; wave-coherent break uses the wave max of all 4 elements
    unsigned qb4[4] = {0u, 0u, 0u, 0u};
    if (i < P4) {
        float4 qv = bv4[i];
        qb4[0] = __float_as_uint(qv.x); qb4[1] = __float_as_uint(qv.y);
        qb4[2] = __float_as_uint(qv.z); qb4[3] = __float_as_uint(qv.w);
    }
    unsigned wqb = max(max(qb4[0], qb4[1]), max(qb4[2], qb4[3]));
    #pragma unroll
    for (int off = 32; off > 0; off >>= 1)
        wqb = max(wqb, (unsigned)__shfl_xor((int)wqb, off));
    if (i < P4 && wqb >= minthr) {
        #pragma unroll
        for (int e = 0; e < 4; ++e) {
            unsigned qb = qb4[e];
            if (qb < minthr) continue;
            int p = 4 * i + e;
            float4 pc = pr_cxcy[p];
            float px1 = pc.x - pc.z * 0.5f, py1 = pc.y - pc.w * 0.5f;
            float px2 = pc.x + pc.z * 0.5f, py2 = pc.y + pc.w * 0.5f;
            float pa = (px2 - px1) * (py2 - py1);
            for (int jj = 0; jj < MM; ++jj) {
                if (thrs[jj] > wqb) break;    // WAVE-uniform: all lanes exit
                if (qb < thrs[jj]) continue;  // lane-level gate
                int j = (int)order[jj];
                float4 bxm = sbox[j];
                if (pc.x < bxm.x - WMARG || pc.x > bxm.z + WMARG ||
                    pc.y < bxm.y - WMARG || pc.y > bxm.w + WMARG) continue;
                float lx = fmaxf(bxm.x, px1), ly = fmaxf(bxm.y, py1);
                float rx = fminf(bxm.z, px2), ry = fminf(bxm.w, py2);
                float iw = fmaxf(rx - lx, 0.0f), ih = fmaxf(ry - ly, 0.0f);
                float inter = iw * ih;
                float den = sarea[j] + pa - inter;
                float qa = inter * __builtin_amdgcn_rcpf(den);
                unsigned hi = (unsigned)(vsm[j] >> 32);
                if (__float_as_uint(qa) + RCPM < hi) continue;
                float q = inter / den;   // reference-exact rounded quotient
                unsigned long long key =
                    ((unsigned long long)__float_as_uint(q) << 32) | (unsigned int)(~p);
                if (key > vsm[j]) atomicMax(&smax[j], key);   // stale-read safe
            }
        }
    }
    __syncthreads();
    if (tid < MM) atomicMax(&Lm[b * MM + tid], smax[tid]);
}

// ---------------- select helpers ----------------
__device__ __forceinline__ float block_sum(float v, float* fred, int tid) {
    fred[tid] = v;
    __syncthreads();
    for (int s = 128; s > 0; s >>= 1) {
        if (tid < s) fred[tid] += fred[tid + s];
        __syncthreads();
    }
    float r = fred[0];
    __syncthreads();
    return r;
}

template <int NB>
__device__ __forceinline__ void suffix_find(const int* __restrict__ h, int K, int tid,
                                            int* iscr, int* bcast, int slot) {
    const int c = NB / 256;
    const int base = tid * c;
    int tsum = 0;
    #pragma unroll
    for (int i = 0; i < c; ++i) tsum += h[base + i];
    iscr[tid] = tsum;
    __syncthreads();
    int val = tsum;                       // Hillis-Steele inclusive suffix scan
    for (int off = 1; off < 256; off <<= 1) {
        int other = (tid + off < 256) ? iscr[tid + off] : 0;
        __syncthreads();
        val += other;
        iscr[tid] = val;
        __syncthreads();
    }
    int acc = val - tsum;
    int best = -1, cg = 0;
    for (int i = base + c - 1; i >= base; --i) {
        int s = acc + h[i];
        if (s >= K) { best = i; cg = acc; break; }
        acc = s;
    }
    iscr[tid] = best;
    __syncthreads();
    for (int s2 = 128; s2 > 0; s2 >>= 1) {
        if (tid < s2) iscr[tid] = max(iscr[tid], iscr[tid + s2]);
        __syncthreads();
    }
    int gbest = iscr[0];
    __syncthreads();
    if (best == gbest && best >= 0) { bcast[slot] = gbest; bcast[slot + 1] = cg; }
    __syncthreads();
}

// ---------------- k_selKF: fused force-assign fix + per-image K + level-1 bucket ----------------
__global__ void k_selKF(const float4* __restrict__ boxes,
                        const float4* __restrict__ pr_cxcy,
                        const float4* __restrict__ plocs,
                        const float2* __restrict__ scores,
                        const unsigned long long* __restrict__ Lm,
                        const float* __restrict__ bestv,
                        const int* __restrict__ bmv,
                        float* __restrict__ confneg,
                        const int* __restrict__ ghist,
                        const int* __restrict__ npos_part,
                        int4* __restrict__ selp,
                        int* __restrict__ npfix,
                        float* __restrict__ cposfix,
                        float* __restrict__ llocfix) {
    int b = blockIdx.x, tid = threadIdx.x;
    __shared__ int h[2048];
    __shared__ int iscr[256];
    __shared__ int bcast[8];
    __shared__ int s_dnp;
    for (int i = tid; i < 2048; i += 256) h[i] = ghist[b * 2048 + i];
    __syncthreads();
    if (tid < 64) {   // wave 0: force-assign deltas
        int fp = -1;
        if (tid < MM) fp = (int)(~(unsigned)(Lm[b * MM + tid] & 0xFFFFFFFFull));
        bool active = (tid < MM);
        for (int m2 = 0; m2 < MM; ++m2) {
            int v = __shfl(fp, m2);
            if (m2 > tid && v == fp) active = false;   // last m wins
        }
        int dnp = 0;
        float dcp = 0.0f, dll = 0.0f;
        if (active) {
            size_t idx = (size_t)b * PP + fp;
            float bo = bestv[idx];
            bool npold = (bo >= THRESH);
            float4 pc = pr_cxcy[fp];
            float4 pl = plocs[idx];
            float llnew = l1loc(boxes[b * MM + tid], pc, pl);
            if (npold) {
                dll = llnew - l1loc(boxes[b * MM + bmv[idx]], pc, pl);
            } else {
                float2 sc = scores[idx];
                float mx = fmaxf(sc.x, sc.y);
                float lse = mx + logf(expf(sc.x - mx) + expf(sc.y - mx));
                dnp = 1;
                dcp = lse - sc.y;
                dll = llnew;
                float cold = confneg[idx];
                atomicAdd(&h[(int)(__float_as_uint(cold) >> 20)], -1);   // LDS
                atomicAdd(&h[0], 1);
                confneg[idx] = 0.0f;   // visible to k_selA (later kernel)
            }
        }
        #pragma unroll
        for (int off = 32; off > 0; off >>= 1) {
            dnp += __shfl_xor(dnp, off);
            dcp += __shfl_xor(dcp, off);
            dll += __shfl_xor(dll, off);
        }
        if (tid == 0) {
            s_dnp = dnp;
            npfix[b] = dnp; cposfix[b] = dcp; llocfix[b] = dll;
        }
    }
    __syncthreads();
    iscr[tid] = (tid < NBLK) ? npos_part[b * NBLK + tid] : 0;
    __syncthreads();
    for (int s = 128; s > 0; s >>= 1) {
        if (tid < s) iscr[tid] += iscr[tid + s];
        __syncthreads();
    }
    int npos = iscr[0] + s_dnp;
    __syncthreads();
    long long Kl = 3LL * npos;
    int K = (Kl > PP) ? PP : (int)Kl;
    if (K == 0) {
        if (tid == 0) selp[b] = make_int4(0, -1, 0, 0);
        return;
    }
    suffix_find<2048>(h, K, tid, iscr, bcast, 0);
    if (tid == 0) {
        int b1 = bcast[0];
        selp[b] = make_int4(K, b1, K - bcast[1], h[b1]);
    }
}

// ---------------- k_selA: parallel confneg sweep, LDS-aggregated ----------------
__global__ void k_selA(const float* __restrict__ confneg,
                       const int4* __restrict__ selp,
                       float* __restrict__ saP,
                       int* __restrict__ ghist2,
                       int* __restrict__ gcur,
                       float* __restrict__ gstore) {
    int b = blockIdx.y, c = blockIdx.x, tid = threadIdx.x;
    __shared__ float fred[256];
    __shared__ int h2[1024];
    __shared__ float sstore[SCH4 * 4];   // 3072 floats: block's chunk worst case
    __shared__ int scnt, sbase;
    for (int i = tid; i < 1024; i += 256) h2[i] = 0;
    if (tid == 0) scnt = 0;
    __syncthreads();
    int4 sp = selp[b];
    int b1 = sp.y;
    float sa = 0.0f;
    if (b1 >= 0) {
        const float4* cn4 = (const float4*)(confneg + (size_t)b * PP);
        int i1 = min((c + 1) * SCH4, P4);
        for (int i = c * SCH4 + tid; i < i1; i += 256) {
            float4 q = cn4[i];
            float vv[4] = {q.x, q.y, q.z, q.w};
            #pragma unroll
            for (int j = 0; j < 4; ++j) {
                unsigned k = __float_as_uint(vv[j]);
                int t11 = (int)(k >> 20);
                if (t11 > b1) sa += vv[j];
                else if (t11 == b1) {
                    atomicAdd(&h2[(k >> 10) & 1023], 1);
                    int ix = atomicAdd(&scnt, 1);   // LDS counter: fast
                    sstore[ix] = vv[j];
                }
            }
        }
    }
    __syncthreads();
    if (tid == 0 && scnt > 0) sbase = atomicAdd(&gcur[b], scnt);   // ONE per block
    __syncthreads();
    int n = scnt;
    for (int i = tid; i < n; i += 256)
        gstore[(size_t)b * CAP + sbase + i] = sstore[i];           // coalesced
    for (int i = tid; i < 1024; i += 256) {
        int v = h2[i];
        if (v) atomicAdd(&ghist2[b * 1024 + i], v);                // nonzero bins only
    }
    float Sa = block_sum(sa, fred, tid);
    if (tid == 0) saP[b * SELCH + c] = Sa;
}

// ---------------- k_selB: levels 2-3 from collected values ----------------
__global__ void k_selB(const int4* __restrict__ selp,
                       const float* __restrict__ saP,
                       const int* __restrict__ ghist2,
                       const float* __restrict__ gstore,
                       float* __restrict__ chard) {
    int b = blockIdx.x, tid = threadIdx.x;
    __shared__ int h[1024];
    __shared__ float fred[256];
    __shared__ int iscr[256];
    __shared__ int bcast[8];
    __shared__ float sSa;
    int4 sp = selp[b];
    if (sp.x == 0) {
        if (tid == 0) chard[b] = 0.0f;
        return;
    }
    int b1 = sp.y, K1 = sp.z, h1cnt = sp.w;
    if (tid == 0) {   // deterministic fixed-order Sa merge
        float s = 0.0f;
        for (int j = 0; j < SELCH; ++j) s += saP[b * SELCH + j];
        sSa = s;
    }
    for (int i = tid; i < 1024; i += 256) h[i] = ghist2[b * 1024 + i];
    __syncthreads();
    float Sa = sSa;
    suffix_find<1024>(h, K1, tid, iscr, bcast, 0);
    int b2 = bcast[0];
    int K2 = K1 - bcast[1];
    unsigned top21 = ((unsigned)b1 << 10) | (unsigned)b2;
    __syncthreads();

    const float* gs = gstore + (size_t)b * CAP;
    for (int i = tid; i < 1024; i += 256) h[i] = 0;
    __syncthreads();
    float sb = 0.0f;
    for (int i = tid; i < h1cnt; i += 256) {
        float v = gs[i];
        unsigned k = __float_as_uint(v);
        int n10 = (int)((k >> 10) & 1023);
        if (n10 > b2) sb += v;
        else if (n10 == b2) atomicAdd(&h[k & 1023], 1);
    }
    float Sb = block_sum(sb, fred, tid);
    suffix_find<1024>(h, K2, tid, iscr, bcast, 2);
    int b3 = bcast[2];
    int K3 = K2 - bcast[3];
    float sc = 0.0f;
    for (int i = tid; i < h1cnt; i += 256) {
        float v = gs[i];
        unsigned k = __float_as_uint(v);
        if ((k >> 10) == top21 && (k & 1023) > (unsigned)b3) sc += v;
    }
    float Sc = block_sum(sc, fred, tid);
    if (tid == 0) {
        unsigned kstar = (top21 << 10) | (unsigned)b3;
        chard[b] = Sa + Sb + Sc + (float)K3 * __uint_as_float(kstar);
    }
}

// ---------------- kernel F: final deterministic combine ----------------
__global__ void k_final(const int* __restrict__ npos_part,
                        const float* __restrict__ cpos_part,
                        const float* __restrict__ loc_part,
                        const float* __restrict__ chard,
                        const int* __restrict__ npfix,
                        const float* __restrict__ cposfix,
                        const float* __restrict__ llocfix,
                        float* __restrict__ out) {
    __shared__ int si[256];
    __shared__ float s1[256], s2[256], s3[256];
    int tn = 0; float tc = 0.0f, tl = 0.0f, th = 0.0f;
    for (int i = threadIdx.x; i < BB * NBLK; i += 256) {
        tn += npos_part[i];
        tc += cpos_part[i];
        tl += loc_part[i];
    }
    if (threadIdx.x < BB) {
        th = chard[threadIdx.x];
        tn += npfix[threadIdx.x];
        tc += cposfix[threadIdx.x];
        tl += llocfix[threadIdx.x];
    }
    si[threadIdx.x] = tn; s1[threadIdx.x] = tc; s2[threadIdx.x] = tl; s3[threadIdx.x] = th;
    __syncthreads();
    for (int s = 128; s > 0; s >>= 1) {
        if (threadIdx.x < s) {
            si[threadIdx.x] += si[threadIdx.x + s];
            s1[threadIdx.x] += s1[threadIdx.x + s];
            s2[threadIdx.x] += s2[threadIdx.x + s];
            s3[threadIdx.x] += s3[threadIdx.x + s];
        }
        __syncthreads();
    }
    if (threadIdx.x == 0) {
        float tp = (float)si[0];
        out[0] = (s3[0] + s1[0]) / tp + s2[0] / (tp * 4.0f);
    }
}

extern "C" void kernel_launch(void* const* d_in, const int* in_sizes, int n_in,
                              void* d_out, int out_size, void* d_ws, size_t ws_size,
                              hipStream_t stream) {
    const float4* plocs   = (const float4*)d_in[0];   // (B,P,4)
    const float2* scores  = (const float2*)d_in[1];   // (B,P,2)
    const float4* boxes   = (const float4*)d_in[2];   // (B,M,4)
    const float4* priors  = (const float4*)d_in[3];   // (P,4) cxcywh
    float* out = (float*)d_out;

    char* ws = (char*)d_ws;
    size_t off = 0;
    auto alloc = [&](size_t bytes) -> void* {
        void* p = ws + off;
        off += (bytes + 255) & ~(size_t)255;
        return p;
    };
    float*              confneg = (float*) alloc((size_t)BB * PP * 4);
    float*              bestv   = (float*) alloc((size_t)BB * PP * 4);
    int*                bmv     = (int*)   alloc((size_t)BB * PP * 4);
    int*                ghist   = (int*)   alloc((size_t)BB * 2048 * 4);
    int*                ghist2  = (int*)   alloc((size_t)BB * 1024 * 4);
    unsigned long long* Lm      = (unsigned long long*)alloc((size_t)BB * MM * 8);
    int*                npos_p  = (int*)   alloc((size_t)BB * NBLK * 4);
    float*              cpos_p  = (float*) alloc((size_t)BB * NBLK * 4);
    float*              loc_p   = (float*) alloc((size_t)BB * NBLK * 4);
    float*              chard   = (float*) alloc((size_t)BB * 4);
    int*                npfix   = (int*)   alloc((size_t)BB * 4);
    float*              cposfix = (float*) alloc((size_t)BB * 4);
    float*              llocfix = (float*) alloc((size_t)BB * 4);
    int4*               selp    = (int4*)  alloc((size_t)BB * 16);
    float*              saP     = (float*) alloc((size_t)BB * SELCH * 4);
    int*                gcur    = (int*)   alloc((size_t)BB * 4);
    float*              gstore  = (float*) alloc((size_t)BB * CAP * 4);
    (void)ws_size; (void)in_sizes; (void)n_in; (void)out_size;

    k_init<<<512, 256, 0, stream>>>(ghist, ghist2, gcur, Lm);
    k_main<<<dim3(NBLK, BB), 256, 0, stream>>>(boxes, priors, plocs, scores,
                                               Lm, bestv, bmv, confneg, ghist,
                                               npos_p, cpos_p, loc_p);
    k_bpo3<<<dim3(NCH, BB), 256, 0, stream>>>(boxes, priors, bestv, Lm);
    k_selKF<<<BB, 256, 0, stream>>>(boxes, priors, plocs, scores, Lm, bestv, bmv,
                                    confneg, ghist, npos_p, selp,
                                    npfix, cposfix, llocfix);
    k_selA<<<dim3(SELCH, BB), 256, 0, stream>>>(confneg, selp, saP, ghist2, gcur, gstore);
    k_selB<<<BB, 256, 0, stream>>>(selp, saP, ghist2, gstore, chard);
    k_final<<<1, 256, 0, stream>>>(npos_p, cpos_p, loc_p, chard,
                                   npfix, cposfix, llocfix, out);
}

// Round 18
// 139.650 us; speedup vs baseline: 1.1570x; 1.1570x over previous
//
#include <hip/hip_runtime.h>
#include <math.h>

// Problem constants (from reference setup_inputs)
#define BB 64
#define MM 50
#define PP 24564
#define NBLK 96                   // ceil(PP/256)
#define THRESH 0.2f
#define P4 (PP / 4)               // 6141 float4s, exact
#define SLACK 64u                 // ulp slack on the bestv filter
#define NCH 24                    // prior chunks in k_bpo3 (24*256 >= P4)
#define WMARG 0.151f              // max prior half-extent 0.15 + eps
#define RCPM 8u                   // ulp margin for rcp pre-compare
#define SELCH 8                   // confneg chunks in k_selA
#define SCH4 ((P4 + SELCH - 1) / SELCH)   // 768 float4 = 3072 values per block
#define CAP PP                    // full-capacity collection: never overflows

// SSD loc-encoding L1 term (identical formula/bits in k_main and k_selKF)
__device__ __forceinline__ float l1loc(float4 bxm, float4 pc, float4 pl) {
    float cx = (bxm.x + bxm.z) * 0.5f, cy = (bxm.y + bxm.w) * 0.5f;
    float w = bxm.z - bxm.x, h = bxm.w - bxm.y;
    float g0 = (cx - pc.x) / (pc.z * 0.1f);
    float g1 = (cy - pc.y) / (pc.w * 0.1f);
    float g2 = logf(w / pc.z) * 5.0f;
    float g3 = logf(h / pc.w) * 5.0f;
    return fabsf(pl.x - g0) + fabsf(pl.y - g1) + fabsf(pl.z - g2) + fabsf(pl.w - g3);
}

// ---------------- k_init: zero ghist/ghist2/gcur, init Lm ----------------
__global__ void k_init(int* __restrict__ ghist, int* __restrict__ ghist2,
                       int* __restrict__ gcur, unsigned long long* __restrict__ Lm) {
    int i = blockIdx.x * 256 + threadIdx.x;   // 512*256 = 131072 threads
    if (i < BB * 2048) ghist[i] = 0;
    if (i < BB * 1024) ghist2[i] = 0;
    if (i < BB) gcur[i] = 0;
    if (i < BB * MM) Lm[i] = 0x00000000FFFFFFFFull;   // q=+0.0, ~p with p=0
}

// ---------------- k_main: per-prior argmax + mutual row-max + CE/loc/hist ----------------
// R11 structure: boxes+areas staged once in LDS, bm-only tracking.
__global__ void k_main(const float4* __restrict__ boxes,
                       const float4* __restrict__ pr_cxcy,
                       const float4* __restrict__ plocs,
                       const float2* __restrict__ scores,
                       unsigned long long* __restrict__ Lm,
                       float* __restrict__ bestv,
                       int* __restrict__ bmv,
                       float* __restrict__ confneg,
                       int* __restrict__ ghist,
                       int* __restrict__ npos_part,
                       float* __restrict__ cpos_part,
                       float* __restrict__ loc_part) {
    int b = blockIdx.y;
    int p = blockIdx.x * 256 + threadIdx.x;
    int tid = threadIdx.x;
    __shared__ float4 sbox[MM];
    __shared__ float sarea[MM];
    __shared__ unsigned long long smax[MM];
    __shared__ int shist[2048];
    __shared__ int si[256];
    __shared__ float s1[256], s2[256];
    for (int i = tid; i < 2048; i += 256) shist[i] = 0;
    if (tid < MM) {
        float4 bxt = boxes[b * MM + tid];
        sbox[tid] = bxt;
        sarea[tid] = (bxt.z - bxt.x) * (bxt.w - bxt.y);
        smax[tid] = 0ull;
    }
    __syncthreads();

    int np = 0;
    float cpos = 0.0f, lloc = 0.0f;
    if (p < PP) {
        float4 pc = pr_cxcy[p];
        float px1 = pc.x - pc.z * 0.5f, py1 = pc.y - pc.w * 0.5f;
        float px2 = pc.x + pc.z * 0.5f, py2 = pc.y + pc.w * 0.5f;
        float pa = (px2 - px1) * (py2 - py1);   // reference rounding (area from corners)
        float binter = 0.0f, bdenom = 1.0f;
        int bm = 0;
        for (int m = 0; m < MM; ++m) {
            float4 bxm = sbox[m];
            float lx = fmaxf(bxm.x, px1), ly = fmaxf(bxm.y, py1);
            float rx = fminf(bxm.z, px2), ry = fminf(bxm.w, py2);
            float iw = fmaxf(rx - lx, 0.0f), ih = fmaxf(ry - ly, 0.0f);
            float inter = iw * ih;
            float den = sarea[m] + pa - inter;
            // inter/den > binter/bdenom  <=>  inter*bdenom > binter*den
            float l = inter * bdenom, r = binter * den;
            if (l > r) { binter = inter; bdenom = den; bm = m; }
        }
        float q = binter / bdenom;   // reference's rounded matrix entry
        size_t idx = (size_t)b * PP + p;
        bestv[idx] = q;
        bmv[idx] = bm;
        unsigned long long key =
            ((unsigned long long)__float_as_uint(q) << 32) | (unsigned int)(~p);
        atomicMax(&smax[bm], key);   // mutual init for row-max pruning
        bool pos = (q >= THRESH);
        float2 sc = scores[idx];
        float mx = fmaxf(sc.x, sc.y);
        float lse = mx + logf(expf(sc.x - mx) + expf(sc.y - mx));
        float conf = pos ? (lse - sc.y) : (lse - sc.x);   // -logp[label]
        float ck = pos ? 0.0f : conf;
        confneg[idx] = ck;
        atomicAdd(&shist[__float_as_uint(ck) >> 20], 1);
        if (pos) {
            np = 1;
            cpos = conf;
            lloc = l1loc(sbox[bm], pc, plocs[idx]);
        }
    }
    si[tid] = np; s1[tid] = cpos; s2[tid] = lloc;
    __syncthreads();
    for (int s = 128; s > 0; s >>= 1) {
        if (tid < s) {
            si[tid] += si[tid + s];
            s1[tid] += s1[tid + s];
            s2[tid] += s2[tid + s];
        }
        __syncthreads();
    }
    if (tid == 0) {
        int o = b * NBLK + blockIdx.x;
        npos_part[o] = si[0];
        cpos_part[o] = s1[0];
        loc_part[o] = s2[0];
    }
    if (tid < MM) {
        unsigned long long v = smax[tid];
        if (v) atomicMax(&Lm[b * MM + tid], v);
    }
    for (int i = tid; i < 2048; i += 256) {
        int c = shist[i];
        if (c) atomicAdd(&ghist[b * 2048 + i], c);
    }
}

// ---------------- k_bpo3: pruned completion, jj-OUTER loop ----------------
// Per-object LDS data read ONCE per jj (amortized over 4 elements in registers).
// Non-volatile 4B smax-hi snapshot gates divs (monotone lower bound: stale-safe).
__global__ void k_bpo3(const float4* __restrict__ boxes,
                       const float4* __restrict__ pr_cxcy,
                       const float* __restrict__ bestv,
                       unsigned long long* __restrict__ Lm) {
    int b = blockIdx.y, c = blockIdx.x, tid = threadIdx.x;
    __shared__ float4 sbox[MM];
    __shared__ float sarea[MM];
    __shared__ unsigned thr[MM];
    __shared__ unsigned thrs[MM];         // thr sorted ascending
    __shared__ unsigned char order[MM];   // object index at each sorted rank
    __shared__ unsigned long long smax[MM];
    if (tid < MM) {
        float4 bxt = boxes[b * MM + tid];
        sbox[tid] = bxt;
        sarea[tid] = (bxt.z - bxt.x) * (bxt.w - bxt.y);
        unsigned long long L = Lm[b * MM + tid];
        smax[tid] = L;
        unsigned hi = (unsigned)(L >> 32);
        thr[tid] = (hi > SLACK) ? hi - SLACK : 0u;
    }
    __syncthreads();
    if (tid < MM) {   // rank sort (deterministic, ties by index)
        unsigned tj = thr[tid];
        int rank = 0;
        for (int k = 0; k < MM; ++k) {
            unsigned tk = thr[k];
            if (tk < tj || (tk == tj && k < tid)) rank++;
        }
        order[rank] = (unsigned char)tid;
        thrs[rank] = tj;
    }
    __syncthreads();
    const unsigned* smax_hi = ((const unsigned*)smax) + 1;   // stride-2 hi words
    const float4* bv4 = (const float4*)(bestv + (size_t)b * PP);
    int i = c * 256 + tid;
    // preload 4 priors into registers (OOB -> qb=0, pc out of range)
    unsigned qb4[4] = {0u, 0u, 0u, 0u};
    float4 pc4[4];
    float px1r[4], py1r[4], px2r[4], py2r[4], par[4];
    #pragma unroll
    for (int e = 0; e < 4; ++e) pc4[e] = make_float4(-10.0f, -10.0f, 0.0f, 0.0f);
    if (i < P4) {
        float4 qv = bv4[i];
        qb4[0] = __float_as_uint(qv.x); qb4[1] = __float_as_uint(qv.y);
        qb4[2] = __float_as_uint(qv.z); qb4[3] = __float_as_uint(qv.w);
        #pragma unroll
        for (int e = 0; e < 4; ++e) pc4[e] = pr_cxcy[4 * i + e];
    }
    #pragma unroll
    for (int e = 0; e < 4; ++e) {
        px1r[e] = pc4[e].x - pc4[e].z * 0.5f;
        py1r[e] = pc4[e].y - pc4[e].w * 0.5f;
        px2r[e] = pc4[e].x + pc4[e].z * 0.5f;
        py2r[e] = pc4[e].y + pc4[e].w * 0.5f;
        par[e] = (px2r[e] - px1r[e]) * (py2r[e] - py1r[e]);
    }
    unsigned wqb = max(max(qb4[0], qb4[1]), max(qb4[2], qb4[3]));
    #pragma unroll
    for (int off = 32; off > 0; off >>= 1)
        wqb = max(wqb, (unsigned)__shfl_xor((int)wqb, off));

    for (int jj = 0; jj < MM; ++jj) {
        unsigned thrv = thrs[jj];
        if (thrv > wqb) break;            // wave-uniform early exit
        int j = (int)order[jj];
        float4 bxm = sbox[j];             // once per jj, shared by 4 elements
        float am = sarea[j];
        unsigned hi = smax_hi[2 * j];     // snapshot (monotone lower bound)
        unsigned long long hikey = ((unsigned long long)hi) << 32;
        #pragma unroll
        for (int e = 0; e < 4; ++e) {
            if (qb4[e] < thrv) continue;
            float4 pc = pc4[e];
            if (pc.x < bxm.x - WMARG || pc.x > bxm.z + WMARG ||
                pc.y < bxm.y - WMARG || pc.y > bxm.w + WMARG) continue;
            float lx = fmaxf(bxm.x, px1r[e]), ly = fmaxf(bxm.y, py1r[e]);
            float rx = fminf(bxm.z, px2r[e]), ry = fminf(bxm.w, py2r[e]);
            float iw = fmaxf(rx - lx, 0.0f), ih = fmaxf(ry - ly, 0.0f);
            float inter = iw * ih;
            float den = am + par[e] - inter;
            float qa = inter * __builtin_amdgcn_rcpf(den);
            if (__float_as_uint(qa) + RCPM < hi) continue;   // can't beat snapshot
            float q = inter / den;        // reference-exact rounded quotient
            unsigned long long key =
                ((unsigned long long)__float_as_uint(q) << 32) |
                (unsigned int)(~(4 * i + e));
            if (key > hikey) atomicMax(&smax[j], key);   // snapshot-gated, stale-safe
        }
    }
    __syncthreads();
    if (tid < MM) atomicMax(&Lm[b * MM + tid], smax[tid]);
}

// ---------------- select helpers ----------------
__device__ __forceinline__ float block_sum(float v, float* fred, int tid) {
    fred[tid] = v;
    __syncthreads();
    for (int s = 128; s > 0; s >>= 1) {
        if (tid < s) fred[tid] += fred[tid + s];
        __syncthreads();
    }
    float r = fred[0];
    __syncthreads();
    return r;
}

template <int NB>
__device__ __forceinline__ void suffix_find(const int* __restrict__ h, int K, int tid,
                                            int* iscr, int* bcast, int slot) {
    const int c = NB / 256;
    const int base = tid * c;
    int tsum = 0;
    #pragma unroll
    for (int i = 0; i < c; ++i) tsum += h[base + i];
    iscr[tid] = tsum;
    __syncthreads();
    int val = tsum;                       // Hillis-Steele inclusive suffix scan
    for (int off = 1; off < 256; off <<= 1) {
        int other = (tid + off < 256) ? iscr[tid + off] : 0;
        __syncthreads();
        val += other;
        iscr[tid] = val;
        __syncthreads();
    }
    int acc = val - tsum;
    int best = -1, cg = 0;
    for (int i = base + c - 1; i >= base; --i) {
        int s = acc + h[i];
        if (s >= K) { best = i; cg = acc; break; }
        acc = s;
    }
    iscr[tid] = best;
    __syncthreads();
    for (int s2 = 128; s2 > 0; s2 >>= 1) {
        if (tid < s2) iscr[tid] = max(iscr[tid], iscr[tid + s2]);
        __syncthreads();
    }
    int gbest = iscr[0];
    __syncthreads();
    if (best == gbest && best >= 0) { bcast[slot] = gbest; bcast[slot + 1] = cg; }
    __syncthreads();
}

// ---------------- k_selKF: fused force-assign fix + per-image K + level-1 bucket ----------------
__global__ void k_selKF(const float4* __restrict__ boxes,
                        const float4* __restrict__ pr_cxcy,
                        const float4* __restrict__ plocs,
                        const float2* __restrict__ scores,
                        const unsigned long long* __restrict__ Lm,
                        const float* __restrict__ bestv,
                        const int* __restrict__ bmv,
                        float* __restrict__ confneg,
                        const int* __restrict__ ghist,
                        const int* __restrict__ npos_part,
                        int4* __restrict__ selp,
                        int* __restrict__ npfix,
                        float* __restrict__ cposfix,
                        float* __restrict__ llocfix) {
    int b = blockIdx.x, tid = threadIdx.x;
    __shared__ int h[2048];
    __shared__ int iscr[256];
    __shared__ int bcast[8];
    __shared__ int s_dnp;
    for (int i = tid; i < 2048; i += 256) h[i] = ghist[b * 2048 + i];
    __syncthreads();
    if (tid < 64) {   // wave 0: force-assign deltas
        int fp = -1;
        if (tid < MM) fp = (int)(~(unsigned)(Lm[b * MM + tid] & 0xFFFFFFFFull));
        bool active = (tid < MM);
        for (int m2 = 0; m2 < MM; ++m2) {
            int v = __shfl(fp, m2);
            if (m2 > tid && v == fp) active = false;   // last m wins
        }
        int dnp = 0;
        float dcp = 0.0f, dll = 0.0f;
        if (active) {
            size_t idx = (size_t)b * PP + fp;
            float bo = bestv[idx];
            bool npold = (bo >= THRESH);
            float4 pc = pr_cxcy[fp];
            float4 pl = plocs[idx];
            float llnew = l1loc(boxes[b * MM + tid], pc, pl);
            if (npold) {
                dll = llnew - l1loc(boxes[b * MM + bmv[idx]], pc, pl);
            } else {
                float2 sc = scores[idx];
                float mx = fmaxf(sc.x, sc.y);
                float lse = mx + logf(expf(sc.x - mx) + expf(sc.y - mx));
                dnp = 1;
                dcp = lse - sc.y;
                dll = llnew;
                float cold = confneg[idx];
                atomicAdd(&h[(int)(__float_as_uint(cold) >> 20)], -1);   // LDS
                atomicAdd(&h[0], 1);
                confneg[idx] = 0.0f;   // visible to k_selA (later kernel)
            }
        }
        #pragma unroll
        for (int off = 32; off > 0; off >>= 1) {
            dnp += __shfl_xor(dnp, off);
            dcp += __shfl_xor(dcp, off);
            dll += __shfl_xor(dll, off);
        }
        if (tid == 0) {
            s_dnp = dnp;
            npfix[b] = dnp; cposfix[b] = dcp; llocfix[b] = dll;
        }
    }
    __syncthreads();
    iscr[tid] = (tid < NBLK) ? npos_part[b * NBLK + tid] : 0;
    __syncthreads();
    for (int s = 128; s > 0; s >>= 1) {
        if (tid < s) iscr[tid] += iscr[tid + s];
        __syncthreads();
    }
    int npos = iscr[0] + s_dnp;
    __syncthreads();
    long long Kl = 3LL * npos;
    int K = (Kl > PP) ? PP : (int)Kl;
    if (K == 0) {
        if (tid == 0) selp[b] = make_int4(0, -1, 0, 0);
        return;
    }
    suffix_find<2048>(h, K, tid, iscr, bcast, 0);
    if (tid == 0) {
        int b1 = bcast[0];
        selp[b] = make_int4(K, b1, K - bcast[1], h[b1]);
    }
}

// ---------------- k_selA: parallel confneg sweep, LDS-aggregated ----------------
__global__ void k_selA(const float* __restrict__ confneg,
                       const int4* __restrict__ selp,
                       float* __restrict__ saP,
                       int* __restrict__ ghist2,
                       int* __restrict__ gcur,
                       float* __restrict__ gstore) {
    int b = blockIdx.y, c = blockIdx.x, tid = threadIdx.x;
    __shared__ float fred[256];
    __shared__ int h2[1024];
    __shared__ float sstore[SCH4 * 4];   // 3072 floats: block's chunk worst case
    __shared__ int scnt, sbase;
    for (int i = tid; i < 1024; i += 256) h2[i] = 0;
    if (tid == 0) scnt = 0;
    __syncthreads();
    int4 sp = selp[b];
    int b1 = sp.y;
    float sa = 0.0f;
    if (b1 >= 0) {
        const float4* cn4 = (const float4*)(confneg + (size_t)b * PP);
        int i1 = min((c + 1) * SCH4, P4);
        for (int i = c * SCH4 + tid; i < i1; i += 256) {
            float4 q = cn4[i];
            float vv[4] = {q.x, q.y, q.z, q.w};
            #pragma unroll
            for (int j = 0; j < 4; ++j) {
                unsigned k = __float_as_uint(vv[j]);
                int t11 = (int)(k >> 20);
                if (t11 > b1) sa += vv[j];
                else if (t11 == b1) {
                    atomicAdd(&h2[(k >> 10) & 1023], 1);
                    int ix = atomicAdd(&scnt, 1);   // LDS counter: fast
                    sstore[ix] = vv[j];
                }
            }
        }
    }
    __syncthreads();
    if (tid == 0 && scnt > 0) sbase = atomicAdd(&gcur[b], scnt);   // ONE per block
    __syncthreads();
    int n = scnt;
    for (int i = tid; i < n; i += 256)
        gstore[(size_t)b * CAP + sbase + i] = sstore[i];           // coalesced
    for (int i = tid; i < 1024; i += 256) {
        int v = h2[i];
        if (v) atomicAdd(&ghist2[b * 1024 + i], v);                // nonzero bins only
    }
    float Sa = block_sum(sa, fred, tid);
    if (tid == 0) saP[b * SELCH + c] = Sa;
}

// ---------------- k_selB: levels 2-3 from collected values ----------------
__global__ void k_selB(const int4* __restrict__ selp,
                       const float* __restrict__ saP,
                       const int* __restrict__ ghist2,
                       const float* __restrict__ gstore,
                       float* __restrict__ chard) {
    int b = blockIdx.x, tid = threadIdx.x;
    __shared__ int h[1024];
    __shared__ float fred[256];
    __shared__ int iscr[256];
    __shared__ int bcast[8];
    __shared__ float sSa;
    int4 sp = selp[b];
    if (sp.x == 0) {
        if (tid == 0) chard[b] = 0.0f;
        return;
    }
    int b1 = sp.y, K1 = sp.z, h1cnt = sp.w;
    if (tid == 0) {   // deterministic fixed-order Sa merge
        float s = 0.0f;
        for (int j = 0; j < SELCH; ++j) s += saP[b * SELCH + j];
        sSa = s;
    }
    for (int i = tid; i < 1024; i += 256) h[i] = ghist2[b * 1024 + i];
    __syncthreads();
    float Sa = sSa;
    suffix_find<1024>(h, K1, tid, iscr, bcast, 0);
    int b2 = bcast[0];
    int K2 = K1 - bcast[1];
    unsigned top21 = ((unsigned)b1 << 10) | (unsigned)b2;
    __syncthreads();

    const float* gs = gstore + (size_t)b * CAP;
    for (int i = tid; i < 1024; i += 256) h[i] = 0;
    __syncthreads();
    float sb = 0.0f;
    for (int i = tid; i < h1cnt; i += 256) {
        float v = gs[i];
        unsigned k = __float_as_uint(v);
        int n10 = (int)((k >> 10) & 1023);
        if (n10 > b2) sb += v;
        else if (n10 == b2) atomicAdd(&h[k & 1023], 1);
    }
    float Sb = block_sum(sb, fred, tid);
    suffix_find<1024>(h, K2, tid, iscr, bcast, 2);
    int b3 = bcast[2];
    int K3 = K2 - bcast[3];
    float sc = 0.0f;
    for (int i = tid; i < h1cnt; i += 256) {
        float v = gs[i];
        unsigned k = __float_as_uint(v);
        if ((k >> 10) == top21 && (k & 1023) > (unsigned)b3) sc += v;
    }
    float Sc = block_sum(sc, fred, tid);
    if (tid == 0) {
        unsigned kstar = (top21 << 10) | (unsigned)b3;
        chard[b] = Sa + Sb + Sc + (float)K3 * __uint_as_float(kstar);
    }
}

// ---------------- kernel F: final deterministic combine ----------------
__global__ void k_final(const int* __restrict__ npos_part,
                        const float* __restrict__ cpos_part,
                        const float* __restrict__ loc_part,
                        const float* __restrict__ chard,
                        const int* __restrict__ npfix,
                        const float* __restrict__ cposfix,
                        const float* __restrict__ llocfix,
                        float* __restrict__ out) {
    __shared__ int si[256];
    __shared__ float s1[256], s2[256], s3[256];
    int tn = 0; float tc = 0.0f, tl = 0.0f, th = 0.0f;
    for (int i = threadIdx.x; i < BB * NBLK; i += 256) {
        tn += npos_part[i];
        tc += cpos_part[i];
        tl += loc_part[i];
    }
    if (threadIdx.x < BB) {
        th = chard[threadIdx.x];
        tn += npfix[threadIdx.x];
        tc += cposfix[threadIdx.x];
        tl += llocfix[threadIdx.x];
    }
    si[threadIdx.x] = tn; s1[threadIdx.x] = tc; s2[threadIdx.x] = tl; s3[threadIdx.x] = th;
    __syncthreads();
    for (int s = 128; s > 0; s >>= 1) {
        if (threadIdx.x < s) {
            si[threadIdx.x] += si[threadIdx.x + s];
            s1[threadIdx.x] += s1[threadIdx.x + s];
            s2[threadIdx.x] += s2[threadIdx.x + s];
            s3[threadIdx.x] += s3[threadIdx.x + s];
        }
        __syncthreads();
    }
    if (threadIdx.x == 0) {
        float tp = (float)si[0];
        out[0] = (s3[0] + s1[0]) / tp + s2[0] / (tp * 4.0f);
    }
}

extern "C" void kernel_launch(void* const* d_in, const int* in_sizes, int n_in,
                              void* d_out, int out_size, void* d_ws, size_t ws_size,
                              hipStream_t stream) {
    const float4* plocs   = (const float4*)d_in[0];   // (B,P,4)
    const float2* scores  = (const float2*)d_in[1];   // (B,P,2)
    const float4* boxes   = (const float4*)d_in[2];   // (B,M,4)
    const float4* priors  = (const float4*)d_in[3];   // (P,4) cxcywh
    float* out = (float*)d_out;

    char* ws = (char*)d_ws;
    size_t off = 0;
    auto alloc = [&](size_t bytes) -> void* {
        void* p = ws + off;
        off += (bytes + 255) & ~(size_t)255;
        return p;
    };
    float*              confneg = (float*) alloc((size_t)BB * PP * 4);
    float*              bestv   = (float*) alloc((size_t)BB * PP * 4);
    int*                bmv     = (int*)   alloc((size_t)BB * PP * 4);
    int*                ghist   = (int*)   alloc((size_t)BB * 2048 * 4);
    int*                ghist2  = (int*)   alloc((size_t)BB * 1024 * 4);
    unsigned long long* Lm      = (unsigned long long*)alloc((size_t)BB * MM * 8);
    int*                npos_p  = (int*)   alloc((size_t)BB * NBLK * 4);
    float*              cpos_p  = (float*) alloc((size_t)BB * NBLK * 4);
    float*              loc_p   = (float*) alloc((size_t)BB * NBLK * 4);
    float*              chard   = (float*) alloc((size_t)BB * 4);
    int*                npfix   = (int*)   alloc((size_t)BB * 4);
    float*              cposfix = (float*) alloc((size_t)BB * 4);
    float*              llocfix = (float*) alloc((size_t)BB * 4);
    int4*               selp    = (int4*)  alloc((size_t)BB * 16);
    float*              saP     = (float*) alloc((size_t)BB * SELCH * 4);
    int*                gcur    = (int*)   alloc((size_t)BB * 4);
    float*              gstore  = (float*) alloc((size_t)BB * CAP * 4);
    (void)ws_size; (void)in_sizes; (void)n_in; (void)out_size;

    k_init<<<512, 256, 0, stream>>>(ghist, ghist2, gcur, Lm);
    k_main<<<dim3(NBLK, BB), 256, 0, stream>>>(boxes, priors, plocs, scores,
                                               Lm, bestv, bmv, confneg, ghist,
                                               npos_p, cpos_p, loc_p);
    k_bpo3<<<dim3(NCH, BB), 256, 0, stream>>>(boxes, priors, bestv, Lm);
    k_selKF<<<BB, 256, 0, stream>>>(boxes, priors, plocs, scores, Lm, bestv, bmv,
                                    confneg, ghist, npos_p, selp,
                                    npfix, cposfix, llocfix);
    k_selA<<<dim3(SELCH, BB), 256, 0, stream>>>(confneg, selp, saP, ghist2, gcur, gstore);
    k_selB<<<BB, 256, 0, stream>>>(selp, saP, ghist2, gstore, chard);
    k_final<<<1, 256, 0, stream>>>(npos_p, cpos_p, loc_p, chard,
                                   npfix, cposfix, llocfix, out);
}